// Round 7
// baseline (651.599 us; speedup 1.0000x reference)
//
#include <hip/hip_runtime.h>
#include <hip/hip_bf16.h>
#include <stdint.h>

#define TOKENS 4096
#define IN_F   4096
#define OUT_F  11008
#define PACKS  512          // IN_F/8
#define GCOUNT 32           // IN_F/128

#define BM 256
#define BN 256
#define BK 64
#define NKT (IN_F / BK)     // 64

typedef __attribute__((ext_vector_type(8))) short bf16x8;
typedef __attribute__((ext_vector_type(4))) float f32x4;

#define AS1 __attribute__((address_space(1)))
#define AS3 __attribute__((address_space(3)))

static __device__ __forceinline__ short f2bf(float f) {
    union { __hip_bfloat16 h; short s; } u;
    u.h = __float2bfloat16(f);
    return u.s;
}

// ---------------- pre-pass: x fp32 -> bf16 ----------------
__global__ __launch_bounds__(256) void cvt_x_kernel(const float* __restrict__ x,
                                                    short* __restrict__ xb) {
    int i = blockIdx.x * 256 + threadIdx.x;
    const float4* s = (const float4*)x + (size_t)i * 2;
    float4 a = s[0], b = s[1];
    bf16x8 v;
    v[0] = f2bf(a.x); v[1] = f2bf(a.y); v[2] = f2bf(a.z); v[3] = f2bf(a.w);
    v[4] = f2bf(b.x); v[5] = f2bf(b.y); v[6] = f2bf(b.z); v[7] = f2bf(b.w);
    ((bf16x8*)xb)[i] = v;
}

// ---------------- pre-pass: dequant W -> bf16 [OUT_F][IN_F] ----------------
__global__ __launch_bounds__(256) void dequant_w_kernel(const int* __restrict__ qw,
                                                        const int* __restrict__ qz,
                                                        const float* __restrict__ sc,
                                                        short* __restrict__ wb) {
    int i = blockIdx.x * 256 + threadIdx.x;
    int o = i >> 9;
    int p = i & 511;
    int g = p >> 4;
    float z = (float)qz[(size_t)g * OUT_F + o];
    float s = sc[(size_t)g * OUT_F + o];
    float zs = z * s;
    int w = qw[i];
    bf16x8 v;
#pragma unroll
    for (int j = 0; j < 8; ++j) {
        float q = (float)((w >> (4 * j)) & 15);
        v[j] = f2bf(q * s - zs);
    }
    ((bf16x8*)wb)[i] = v;
}

// ---------------- staging helpers (pre-swizzled source -> linear LDS) ----------------
// LDS 16B chunk (row r, chunk c) holds global chunk (c ^ (r&7)).
__device__ __forceinline__ void stage_tile(const short* __restrict__ G, int row0, int kt,
                                           short* lds, int tid) {
#pragma unroll
    for (int i = 0; i < 4; ++i) {
        int CH = i * 512 + tid;                 // chunk 0..2047 (256 rows)
        int r = CH >> 3;
        int sc = (CH & 7) ^ (r & 7);
        const short* g = G + (size_t)(row0 + r) * IN_F + kt + sc * 8;
        __builtin_amdgcn_global_load_lds((const AS1 void*)g,
                                         (AS3 void*)(lds + CH * 8), 16, 0, 0);
    }
}

__device__ __forceinline__ void stage_half(const short* __restrict__ G, int grow0, int kt,
                                           short* ldsh, int tid) {
#pragma unroll
    for (int j = 0; j < 2; ++j) {
        int CH = j * 512 + tid;                 // chunk 0..1023 (128 rows)
        int r = CH >> 3;
        int sc = (CH & 7) ^ (r & 7);
        const short* g = G + (size_t)(grow0 + r) * IN_F + kt + sc * 8;
        __builtin_amdgcn_global_load_lds((const AS1 void*)g,
                                         (AS3 void*)(ldsh + CH * 8), 16, 0, 0);
    }
}

#define QUAD(AF, BF, AO, BO)                                                      \
    __builtin_amdgcn_s_setprio(1);                                                \
    _Pragma("unroll") for (int m = 0; m < 4; ++m)                                 \
    _Pragma("unroll") for (int n = 0; n < 2; ++n)                                 \
    _Pragma("unroll") for (int ks = 0; ks < 2; ++ks)                              \
        acc[(AO) + m][(BO) + n] = __builtin_amdgcn_mfma_f32_16x16x32_bf16(        \
            AF[m][ks], BF[n][ks], acc[(AO) + m][(BO) + n], 0, 0, 0);              \
    __builtin_amdgcn_s_setprio(0);

// ---------------- one K-tile = 4 phases, balanced reads 8/8/8/0 ----------------
// Quads: Q0=(m0-3,n0-1) Q1=(m0-3,n2-3) Q2=(m4-7,n0-1) Q3=(m4-7,n2-3)
// Q2/Q3 of tile t run in ph0/ph1 of tile t+1 (read-ahead, v3 skeleton).
// Ledger: B(t+1)->Bs[cur^1] @ph0/ph1 (B(t-1) reads drained at ph2(t-1) lgkm0);
//   A(t+2)->As[cur] @ph3 (afA/afB(t) drained at ph2(t) lgkm0);
//   vmcnt(4)@ph3 => A(t+1),B(t+1) landed, A(t+2) in flight.
template <int VMN, bool PREV>
__device__ __forceinline__ void ktile(const short* __restrict__ Ag,
                                      const short* __restrict__ Bg,
                                      int row0, int col0, int t, int cur,
                                      short (&As)[2][BM * BK], short (&Bs)[2][BN * BK],
                                      f32x4 (&acc)[8][4],
                                      bf16x8 (&afA)[4][2], bf16x8 (&afB)[4][2],
                                      bf16x8 (&bfA)[2][2], bf16x8 (&bfB)[2][2],
                                      int wm, int wn, int l15, int cs0, int cs1, int tid) {
    const short* At = &As[cur][0];
    const short* Bt = &Bs[cur][0];

    // ---- ph0: stage B0(t+1); read afA(t) [8]; MFMA Q2(t-1) ----
    if (t + 1 < NKT) stage_half(Bg, col0, (t + 1) * BK, &Bs[cur ^ 1][0], tid);
#pragma unroll
    for (int m = 0; m < 4; ++m) {
        int r = (wm * 128 + m * 16 + l15) * BK;
        afA[m][0] = *(const bf16x8*)(At + r + cs0);
        afA[m][1] = *(const bf16x8*)(At + r + cs1);
    }
    __builtin_amdgcn_sched_barrier(0);
    if (PREV) { QUAD(afB, bfA, 4, 0); }
    __builtin_amdgcn_s_barrier();

    // ---- ph1: stage B1(t+1); read bfA(t) [4]; MFMA Q3(t-1); read bfB(t) [4] ----
    if (t + 1 < NKT) stage_half(Bg, col0 + 128, (t + 1) * BK, &Bs[cur ^ 1][128 * BK], tid);
#pragma unroll
    for (int n = 0; n < 2; ++n) {
        int r = (wn * 64 + n * 16 + l15) * BK;
        bfA[n][0] = *(const bf16x8*)(Bt + r + cs0);
        bfA[n][1] = *(const bf16x8*)(Bt + r + cs1);
    }
    __builtin_amdgcn_sched_barrier(0);
    if (PREV) { QUAD(afB, bfB, 4, 2); }        // consumes OLD bfB before reload below
    __builtin_amdgcn_sched_barrier(0);
#pragma unroll
    for (int n = 0; n < 2; ++n) {
        int r = (wn * 64 + (2 + n) * 16 + l15) * BK;
        bfB[n][0] = *(const bf16x8*)(Bt + r + cs0);
        bfB[n][1] = *(const bf16x8*)(Bt + r + cs1);
    }
    __builtin_amdgcn_s_barrier();

    // ---- ph2: read afB(t) [8]; MFMA Q0(t); drain all ds_reads of buf[cur] ----
#pragma unroll
    for (int m = 0; m < 4; ++m) {
        int r = (wm * 128 + (4 + m) * 16 + l15) * BK;
        afB[m][0] = *(const bf16x8*)(At + r + cs0);
        afB[m][1] = *(const bf16x8*)(At + r + cs1);
    }
    __builtin_amdgcn_sched_barrier(0);
    QUAD(afA, bfA, 0, 0);
    asm volatile("s_waitcnt lgkmcnt(0)" ::: "memory");
    __builtin_amdgcn_sched_barrier(0);
    __builtin_amdgcn_s_barrier();

    // ---- ph3: stage A(t+2) into As[cur]; MFMA Q1(t); counted vmcnt ----
    if (t + 2 < NKT) stage_tile(Ag, row0, (t + 2) * BK, &As[cur][0], tid);
    __builtin_amdgcn_sched_barrier(0);
    QUAD(afA, bfB, 0, 2);
    if (VMN == 0) {
        asm volatile("s_waitcnt vmcnt(0)" ::: "memory");
    } else {
        asm volatile("s_waitcnt vmcnt(4)" ::: "memory");
    }
    __builtin_amdgcn_s_barrier();
}

// ---------------- 256x256 balanced pipelined GEMM ----------------
__global__ __launch_bounds__(512, 2) void gemm256_kernel(const short* __restrict__ A,
                                                         const short* __restrict__ B,
                                                         float* __restrict__ C) {
    __shared__ short As[2][BM * BK];            // 2 x 32 KiB
    __shared__ short Bs[2][BN * BK];            // 2 x 32 KiB (128 KiB total)

    const int nbn = OUT_F / BN;                 // 43
    const int nwg = (TOKENS / BM) * nbn;        // 688 = 8*86
    const int cpx = nwg >> 3;
    int bid = blockIdx.x;
    int swz = (bid & 7) * cpx + (bid >> 3);     // XCD-contiguous (bijective)
    int bm = swz / nbn, bn = swz % nbn;
    const int row0 = bm * BM, col0 = bn * BN;

    const int tid = threadIdx.x;
    const int lane = tid & 63;
    const int wid = tid >> 6;                   // 8 waves: 2M x 4N
    const int wm = wid >> 2, wn = wid & 3;
    const int l15 = lane & 15, lhi = lane >> 4, l7 = lane & 7;
    const int cs0 = ((lhi ^ l7) & 7) * 8;       // swizzled chunk for ks0
    const int cs1 = (((4 + lhi) ^ l7) & 7) * 8; // swizzled chunk for ks1

    f32x4 acc[8][4] = {};
    bf16x8 afA[4][2], afB[4][2], bfA[2][2], bfB[2][2];

    // prologue: stage A(0), B(0), A(1); A(0),B(0) landed, A(1) in flight
    stage_tile(A, row0, 0, &As[0][0], tid);
    stage_tile(B, col0, 0, &Bs[0][0], tid);
    stage_tile(A, row0, BK, &As[1][0], tid);
    asm volatile("s_waitcnt vmcnt(4)" ::: "memory");
    __builtin_amdgcn_s_barrier();

    ktile<4, false>(A, B, row0, col0, 0, 0, As, Bs, acc, afA, afB, bfA, bfB,
                    wm, wn, l15, cs0, cs1, tid);
    ktile<4, true>(A, B, row0, col0, 1, 1, As, Bs, acc, afA, afB, bfA, bfB,
                   wm, wn, l15, cs0, cs1, tid);
    for (int i = 1; i < 31; ++i) {
        ktile<4, true>(A, B, row0, col0, 2 * i, 0, As, Bs, acc, afA, afB, bfA, bfB,
                       wm, wn, l15, cs0, cs1, tid);
        ktile<4, true>(A, B, row0, col0, 2 * i + 1, 1, As, Bs, acc, afA, afB, bfA, bfB,
                       wm, wn, l15, cs0, cs1, tid);
    }
    ktile<0, true>(A, B, row0, col0, 62, 0, As, Bs, acc, afA, afB, bfA, bfB,
                   wm, wn, l15, cs0, cs1, tid);
    ktile<0, true>(A, B, row0, col0, 63, 1, As, Bs, acc, afA, afB, bfA, bfB,
                   wm, wn, l15, cs0, cs1, tid);

    // ---- pipeline tail: Q2(63), Q3(63) ----
    { QUAD(afB, bfA, 4, 0); }
    { QUAD(afB, bfB, 4, 2); }

    // ---- epilogue: C write ----
#pragma unroll
    for (int m = 0; m < 8; ++m)
#pragma unroll
        for (int n = 0; n < 4; ++n) {
            int r = row0 + wm * 128 + m * 16 + (lhi << 2);
            int c = col0 + wn * 64 + n * 16 + l15;
#pragma unroll
            for (int j = 0; j < 4; ++j)
                C[(size_t)(r + j) * OUT_F + c] = acc[m][n][j];
        }
}

// ---------------- fallback: fused dequant GEMM (128-tile, known-good) ----------------
__device__ __forceinline__ void mfma_tile128(const short* As, const short* Bs,
                                             f32x4 acc[4][4], int lane, int wm, int wn) {
#pragma unroll
    for (int kk = 0; kk < 64; kk += 32) {
        const int kb = kk + (lane >> 4) * 8;
        bf16x8 af[4], bfr[4];
#pragma unroll
        for (int m = 0; m < 4; ++m) {
            int r = wm * 64 + m * 16 + (lane & 15);
            af[m] = *(const bf16x8*)(As + r * 64 + kb);
        }
#pragma unroll
        for (int n = 0; n < 4; ++n) {
            int c = wn * 64 + n * 16 + (lane & 15);
            bfr[n] = *(const bf16x8*)(Bs + c * 64 + kb);
        }
#pragma unroll
        for (int m = 0; m < 4; ++m)
#pragma unroll
            for (int n = 0; n < 4; ++n)
                acc[m][n] = __builtin_amdgcn_mfma_f32_16x16x32_bf16(af[m], bfr[n],
                                                                    acc[m][n], 0, 0, 0);
    }
}

__global__ __launch_bounds__(256) void gemm_fused_kernel(const float* __restrict__ x,
                                                         const int* __restrict__ qw,
                                                         const int* __restrict__ qz,
                                                         const float* __restrict__ sc,
                                                         float* __restrict__ C) {
    const int nbn = OUT_F / 128;
    const int nwg = (TOKENS / 128) * nbn;
    const int cpx = nwg >> 3;
    int bid = blockIdx.x;
    int swzb = (bid & 7) * cpx + (bid >> 3);
    int bm = swzb / nbn, bn = swzb % nbn;
    const int row0 = bm * 128, col0 = bn * 128;

    __shared__ short As[128 * 64];
    __shared__ short Bs[128 * 64];

    const int tid = threadIdx.x;
    const int lane = tid & 63;
    const int wid = tid >> 6;
    const int wm = wid >> 1, wn = wid & 1;

    f32x4 acc[4][4] = {};

    for (int kt = 0; kt < IN_F; kt += 64) {
#pragma unroll
        for (int i = 0; i < 4; ++i) {
            int idx = i * 256 + tid;
            int r = idx >> 3, kc = (idx & 7) * 8;
            const float4* src = (const float4*)(x + (size_t)(row0 + r) * IN_F + kt + kc);
            float4 a = src[0], b = src[1];
            bf16x8 v;
            v[0] = f2bf(a.x); v[1] = f2bf(a.y); v[2] = f2bf(a.z); v[3] = f2bf(a.w);
            v[4] = f2bf(b.x); v[5] = f2bf(b.y); v[6] = f2bf(b.z); v[7] = f2bf(b.w);
            *(bf16x8*)(As + r * 64 + kc) = v;
        }
        {
            int ol = tid >> 1;
            int kc = (tid & 1) * 32;
            const int4* src = (const int4*)(qw + (size_t)(col0 + ol) * PACKS + ((kt + kc) >> 3));
            int4 w4 = *src;
            int g = kt >> 7;
            float z = (float)qz[(size_t)g * OUT_F + col0 + ol];
            float s = sc[(size_t)g * OUT_F + col0 + ol];
            float zs = z * s;
            const int* wp = (const int*)&w4;
#pragma unroll
            for (int c2 = 0; c2 < 4; ++c2) {
                int w32 = wp[c2];
                bf16x8 v;
#pragma unroll
                for (int j = 0; j < 8; ++j)
                    v[j] = f2bf((float)((w32 >> (4 * j)) & 15) * s - zs);
                *(bf16x8*)(Bs + ol * 64 + kc + c2 * 8) = v;
            }
        }
        __syncthreads();
        mfma_tile128(As, Bs, acc, lane, wm, wn);
        __syncthreads();
    }
#pragma unroll
    for (int m = 0; m < 4; ++m)
#pragma unroll
        for (int n = 0; n < 4; ++n) {
            int r = row0 + wm * 64 + m * 16 + ((lane >> 4) << 2);
            int c = col0 + wn * 64 + n * 16 + (lane & 15);
#pragma unroll
            for (int j = 0; j < 4; ++j)
                C[(size_t)(r + j) * OUT_F + c] = acc[m][n][j];
        }
}

extern "C" void kernel_launch(void* const* d_in, const int* in_sizes, int n_in,
                              void* d_out, int out_size, void* d_ws, size_t ws_size,
                              hipStream_t stream) {
    const float* x = (const float*)d_in[0];
    const int* qw = (const int*)d_in[1];
    const int* qz = (const int*)d_in[2];
    const float* sc = (const float*)d_in[3];
    float* out = (float*)d_out;

    const size_t xb_elems = (size_t)TOKENS * IN_F;
    const size_t wb_elems = (size_t)OUT_F * IN_F;
    const size_t need = (xb_elems + wb_elems) * sizeof(short);

    if (ws_size >= need) {
        short* xb = (short*)d_ws;
        short* wb = xb + xb_elems;
        cvt_x_kernel<<<(TOKENS * IN_F / 8) / 256, 256, 0, stream>>>(x, xb);
        dequant_w_kernel<<<(OUT_F * PACKS) / 256, 256, 0, stream>>>(qw, qz, sc, wb);
        const int ngemm = (TOKENS / BM) * (OUT_F / BN);   // 688
        gemm256_kernel<<<ngemm, 512, 0, stream>>>(xb, wb, out);
    } else {
        const int ngemm = (TOKENS / 128) * (OUT_F / 128);
        gemm_fused_kernel<<<ngemm, 256, 0, stream>>>(x, qw, qz, sc, out);
    }
}

// Round 10
// 395.565 us; speedup vs baseline: 1.6473x; 1.6473x over previous
//
#include <hip/hip_runtime.h>
#include <hip/hip_bf16.h>
#include <stdint.h>

#define TOKENS 4096
#define IN_F   4096
#define OUT_F  11008
#define PACKS  512          // IN_F/8
#define GCOUNT 32           // IN_F/128

#define BM 256
#define BN 256
#define BK 64
#define NKT (IN_F / BK)     // 64

typedef __attribute__((ext_vector_type(8))) short bf16x8;
typedef __attribute__((ext_vector_type(4))) float f32x4;

#define AS1 __attribute__((address_space(1)))
#define AS3 __attribute__((address_space(3)))

static __device__ __forceinline__ short f2bf(float f) {
    union { __hip_bfloat16 h; short s; } u;
    u.h = __float2bfloat16(f);
    return u.s;
}

// ---------------- pre-pass: x fp32 -> bf16 ----------------
__global__ __launch_bounds__(256) void cvt_x_kernel(const float* __restrict__ x,
                                                    short* __restrict__ xb) {
    int i = blockIdx.x * 256 + threadIdx.x;
    const float4* s = (const float4*)x + (size_t)i * 2;
    float4 a = s[0], b = s[1];
    bf16x8 v;
    v[0] = f2bf(a.x); v[1] = f2bf(a.y); v[2] = f2bf(a.z); v[3] = f2bf(a.w);
    v[4] = f2bf(b.x); v[5] = f2bf(b.y); v[6] = f2bf(b.z); v[7] = f2bf(b.w);
    ((bf16x8*)xb)[i] = v;
}

// ---------------- pre-pass: dequant W -> bf16 [OUT_F][IN_F] ----------------
__global__ __launch_bounds__(256) void dequant_w_kernel(const int* __restrict__ qw,
                                                        const int* __restrict__ qz,
                                                        const float* __restrict__ sc,
                                                        short* __restrict__ wb) {
    int i = blockIdx.x * 256 + threadIdx.x;
    int o = i >> 9;
    int p = i & 511;
    int g = p >> 4;
    float z = (float)qz[(size_t)g * OUT_F + o];
    float s = sc[(size_t)g * OUT_F + o];
    float zs = z * s;
    int w = qw[i];
    bf16x8 v;
#pragma unroll
    for (int j = 0; j < 8; ++j) {
        float q = (float)((w >> (4 * j)) & 15);
        v[j] = f2bf(q * s - zs);
    }
    ((bf16x8*)wb)[i] = v;
}

// ---------------- staging: global (pre-swizzled source) -> linear LDS ----------------
// LDS tile [256 rows][64 bf16]; 16B chunk (row r, chunk c) holds global chunk (c ^ (r&7)).
__device__ __forceinline__ void stage_tile(const short* __restrict__ G, int row0, int kt,
                                           short* lds, int tid) {
#pragma unroll
    for (int i = 0; i < 4; ++i) {
        int CH = i * 512 + tid;                 // chunk index 0..2047
        int r = CH >> 3;
        int sc = (CH & 7) ^ (r & 7);            // inverse swizzle on the SOURCE
        const short* g = G + (size_t)(row0 + r) * IN_F + kt + sc * 8;
        __builtin_amdgcn_global_load_lds((const AS1 void*)g,
                                         (AS3 void*)(lds + CH * 8), 16, 0, 0);
    }
}

// ---------------- 256x256 pipelined 4-phase GEMM, A triple-buffered ----------------
// Clusters: Q0=(m0-3,n0-1) Q1=(m0-3,n2-3) Q2=(m4-7,n0-1) Q3=(m4-7,n2-3)
// Reads one phase ahead of use; Q2/Q3 of tile t run in ph0/ph1 of tile t+1.
// As[3] removes the mid-tile lgkmcnt(0): stage A(t+2) targets As[(t+2)%3] =
// A(t-1)'s buffer, whose reads were consumed by Q2/Q3(t-1) at ph0/ph1(t)
// (per-wave operand waits + ph1-end barrier). B(t+1)@ph0 targets B(t-1)'s
// buffer, whose reads were consumed by Q0/Q1(t-1) within tile t-1.
// vmcnt(4)@ph3 => A(t+1),B(t+1) landed; A(t+2) in flight.
__global__ __launch_bounds__(512, 2) void gemm256_kernel(const short* __restrict__ A,
                                                         const short* __restrict__ B,
                                                         float* __restrict__ C) {
    __shared__ short As[3][BM * BK];            // 3 x 32 KiB
    __shared__ short Bs[2][BN * BK];            // 2 x 32 KiB (160 KiB total)

    const int nbn = OUT_F / BN;                 // 43
    const int nwg = (TOKENS / BM) * nbn;        // 688 = 8*86
    const int cpx = nwg >> 3;
    int bid = blockIdx.x;
    int swz = (bid & 7) * cpx + (bid >> 3);     // XCD-contiguous (bijective)
    int bm = swz / nbn, bn = swz % nbn;
    const int row0 = bm * BM, col0 = bn * BN;

    const int tid = threadIdx.x;
    const int lane = tid & 63;
    const int wid = tid >> 6;                   // 8 waves: 2M x 4N
    const int wm = wid >> 2, wn = wid & 3;
    const int l15 = lane & 15, lhi = lane >> 4, l7 = lane & 7;
    const int cs0 = ((lhi ^ l7) & 7) * 8;       // swizzled chunk for ks0
    const int cs1 = (((4 + lhi) ^ l7) & 7) * 8; // swizzled chunk for ks1

    f32x4 acc[8][4] = {};
    bf16x8 afA[4][2], afB[4][2], bfA[2][2], bfB[2][2];

    // prologue: stage A0->As[0], B0->Bs[0], A1->As[1]; A0,B0 landed, A1 in flight
    stage_tile(A, row0, 0, &As[0][0], tid);
    stage_tile(B, col0, 0, &Bs[0][0], tid);
    stage_tile(A, row0, BK, &As[1][0], tid);
    asm volatile("s_waitcnt vmcnt(4)" ::: "memory");
    __builtin_amdgcn_s_barrier();

    int ca = 0;                                 // A buffer of tile t (t % 3)
    for (int t = 0; t < NKT; ++t) {
        const int curB = t & 1;
        const int sa = (ca >= 1) ? ca - 1 : ca + 2;   // (t+2) % 3
        const short* At = &As[ca][0];
        const short* Bt = &Bs[curB][0];

        // ---- phase 0: read afA(t); stage B(t+1); MFMA Q2(t-1) ----
#pragma unroll
        for (int m = 0; m < 4; ++m) {
            int r = (wm * 128 + m * 16 + l15) * BK;
            afA[m][0] = *(const bf16x8*)(At + r + cs0);
            afA[m][1] = *(const bf16x8*)(At + r + cs1);
        }
        if (t < NKT - 1)
            stage_tile(B, col0, (t + 1) * BK, &Bs[curB ^ 1][0], tid);
        __builtin_amdgcn_sched_barrier(0);
        if (t > 0) {
            __builtin_amdgcn_s_setprio(1);
#pragma unroll
            for (int m = 0; m < 4; ++m)
#pragma unroll
                for (int n = 0; n < 2; ++n)
#pragma unroll
                    for (int ks = 0; ks < 2; ++ks)
                        acc[4 + m][n] = __builtin_amdgcn_mfma_f32_16x16x32_bf16(
                            afB[m][ks], bfA[n][ks], acc[4 + m][n], 0, 0, 0);
            __builtin_amdgcn_s_setprio(0);
        }
        __builtin_amdgcn_s_barrier();

        // ---- phase 1: read bfA(t); MFMA Q3(t-1) ----
#pragma unroll
        for (int n = 0; n < 2; ++n) {
            int r = (wn * 64 + n * 16 + l15) * BK;
            bfA[n][0] = *(const bf16x8*)(Bt + r + cs0);
            bfA[n][1] = *(const bf16x8*)(Bt + r + cs1);
        }
        __builtin_amdgcn_sched_barrier(0);
        if (t > 0) {
            __builtin_amdgcn_s_setprio(1);
#pragma unroll
            for (int m = 0; m < 4; ++m)
#pragma unroll
                for (int n = 0; n < 2; ++n)
#pragma unroll
                    for (int ks = 0; ks < 2; ++ks)
                        acc[4 + m][2 + n] = __builtin_amdgcn_mfma_f32_16x16x32_bf16(
                            afB[m][ks], bfB[n][ks], acc[4 + m][2 + n], 0, 0, 0);
            __builtin_amdgcn_s_setprio(0);
        }
        __builtin_amdgcn_s_barrier();

        // ---- phase 2: read bfB(t) then afB(t); MFMA Q0(t); NO drain ----
        // bfB first so Q1's wait is lgkmcnt(8): afB stays in flight into ph0(t+1).
#pragma unroll
        for (int n = 0; n < 2; ++n) {
            int r = (wn * 64 + (2 + n) * 16 + l15) * BK;
            bfB[n][0] = *(const bf16x8*)(Bt + r + cs0);
            bfB[n][1] = *(const bf16x8*)(Bt + r + cs1);
        }
#pragma unroll
        for (int m = 0; m < 4; ++m) {
            int r = (wm * 128 + (4 + m) * 16 + l15) * BK;
            afB[m][0] = *(const bf16x8*)(At + r + cs0);
            afB[m][1] = *(const bf16x8*)(At + r + cs1);
        }
        __builtin_amdgcn_sched_barrier(0);
        __builtin_amdgcn_s_setprio(1);
#pragma unroll
        for (int m = 0; m < 4; ++m)
#pragma unroll
            for (int n = 0; n < 2; ++n)
#pragma unroll
                for (int ks = 0; ks < 2; ++ks)
                    acc[m][n] = __builtin_amdgcn_mfma_f32_16x16x32_bf16(
                        afA[m][ks], bfA[n][ks], acc[m][n], 0, 0, 0);
        __builtin_amdgcn_s_setprio(0);
        __builtin_amdgcn_s_barrier();

        // ---- phase 3: stage A(t+2) into As[sa]; MFMA Q1(t); counted vmcnt ----
        if (t < NKT - 2)
            stage_tile(A, row0, (t + 2) * BK, &As[sa][0], tid);
        __builtin_amdgcn_sched_barrier(0);
        __builtin_amdgcn_s_setprio(1);
#pragma unroll
        for (int m = 0; m < 4; ++m)
#pragma unroll
            for (int n = 0; n < 2; ++n)
#pragma unroll
                for (int ks = 0; ks < 2; ++ks)
                    acc[m][2 + n] = __builtin_amdgcn_mfma_f32_16x16x32_bf16(
                        afA[m][ks], bfB[n][ks], acc[m][2 + n], 0, 0, 0);
        __builtin_amdgcn_s_setprio(0);
        if (t < NKT - 2) {
            asm volatile("s_waitcnt vmcnt(4)" ::: "memory");   // t+1 landed; A(t+2) in flight
        } else if (t == NKT - 2) {
            asm volatile("s_waitcnt vmcnt(0)" ::: "memory");   // everything landed for t=63
        }
        __builtin_amdgcn_s_barrier();

        ca = (ca == 2) ? 0 : ca + 1;
    }

    // ---- pipeline tail: Q2(63), Q3(63) ----
#pragma unroll
    for (int m = 0; m < 4; ++m)
#pragma unroll
        for (int n = 0; n < 2; ++n)
#pragma unroll
            for (int ks = 0; ks < 2; ++ks) {
                acc[4 + m][n] = __builtin_amdgcn_mfma_f32_16x16x32_bf16(
                    afB[m][ks], bfA[n][ks], acc[4 + m][n], 0, 0, 0);
                acc[4 + m][2 + n] = __builtin_amdgcn_mfma_f32_16x16x32_bf16(
                    afB[m][ks], bfB[n][ks], acc[4 + m][2 + n], 0, 0, 0);
            }

    // ---- epilogue: C write ----
#pragma unroll
    for (int m = 0; m < 8; ++m)
#pragma unroll
        for (int n = 0; n < 4; ++n) {
            int r = row0 + wm * 128 + m * 16 + (lhi << 2);
            int c = col0 + wn * 64 + n * 16 + l15;
#pragma unroll
            for (int j = 0; j < 4; ++j)
                C[(size_t)(r + j) * OUT_F + c] = acc[m][n][j];
        }
}

// ---------------- fallback: fused dequant GEMM (128-tile, known-good) ----------------
__device__ __forceinline__ void mfma_tile128(const short* As, const short* Bs,
                                             f32x4 acc[4][4], int lane, int wm, int wn) {
#pragma unroll
    for (int kk = 0; kk < 64; kk += 32) {
        const int kb = kk + (lane >> 4) * 8;
        bf16x8 af[4], bfr[4];
#pragma unroll
        for (int m = 0; m < 4; ++m) {
            int r = wm * 64 + m * 16 + (lane & 15);
            af[m] = *(const bf16x8*)(As + r * 64 + kb);
        }
#pragma unroll
        for (int n = 0; n < 4; ++n) {
            int c = wn * 64 + n * 16 + (lane & 15);
            bfr[n] = *(const bf16x8*)(Bs + c * 64 + kb);
        }
#pragma unroll
        for (int m = 0; m < 4; ++m)
#pragma unroll
            for (int n = 0; n < 4; ++n)
                acc[m][n] = __builtin_amdgcn_mfma_f32_16x16x32_bf16(af[m], bfr[n],
                                                                    acc[m][n], 0, 0, 0);
    }
}

__global__ __launch_bounds__(256) void gemm_fused_kernel(const float* __restrict__ x,
                                                         const int* __restrict__ qw,
                                                         const int* __restrict__ qz,
                                                         const float* __restrict__ sc,
                                                         float* __restrict__ C) {
    const int nbn = OUT_F / 128;
    const int nwg = (TOKENS / 128) * nbn;
    const int cpx = nwg >> 3;
    int bid = blockIdx.x;
    int swzb = (bid & 7) * cpx + (bid >> 3);
    int bm = swzb / nbn, bn = swzb % nbn;
    const int row0 = bm * 128, col0 = bn * 128;

    __shared__ short As[128 * 64];
    __shared__ short Bs[128 * 64];

    const int tid = threadIdx.x;
    const int lane = tid & 63;
    const int wid = tid >> 6;
    const int wm = wid >> 1, wn = wid & 1;

    f32x4 acc[4][4] = {};

    for (int kt = 0; kt < IN_F; kt += 64) {
#pragma unroll
        for (int i = 0; i < 4; ++i) {
            int idx = i * 256 + tid;
            int r = idx >> 3, kc = (idx & 7) * 8;
            const float4* src = (const float4*)(x + (size_t)(row0 + r) * IN_F + kt + kc);
            float4 a = src[0], b = src[1];
            bf16x8 v;
            v[0] = f2bf(a.x); v[1] = f2bf(a.y); v[2] = f2bf(a.z); v[3] = f2bf(a.w);
            v[4] = f2bf(b.x); v[5] = f2bf(b.y); v[6] = f2bf(b.z); v[7] = f2bf(b.w);
            *(bf16x8*)(As + r * 64 + kc) = v;
        }
        {
            int ol = tid >> 1;
            int kc = (tid & 1) * 32;
            const int4* src = (const int4*)(qw + (size_t)(col0 + ol) * PACKS + ((kt + kc) >> 3));
            int4 w4 = *src;
            int g = kt >> 7;
            float z = (float)qz[(size_t)g * OUT_F + col0 + ol];
            float s = sc[(size_t)g * OUT_F + col0 + ol];
            float zs = z * s;
            const int* wp = (const int*)&w4;
#pragma unroll
            for (int c2 = 0; c2 < 4; ++c2) {
                int w32 = wp[c2];
                bf16x8 v;
#pragma unroll
                for (int j = 0; j < 8; ++j)
                    v[j] = f2bf((float)((w32 >> (4 * j)) & 15) * s - zs);
                *(bf16x8*)(Bs + ol * 64 + kc + c2 * 8) = v;
            }
        }
        __syncthreads();
        mfma_tile128(As, Bs, acc, lane, wm, wn);
        __syncthreads();
    }
#pragma unroll
    for (int m = 0; m < 4; ++m)
#pragma unroll
        for (int n = 0; n < 4; ++n) {
            int r = row0 + wm * 64 + m * 16 + ((lane >> 4) << 2);
            int c = col0 + wn * 64 + n * 16 + (lane & 15);
#pragma unroll
            for (int j = 0; j < 4; ++j)
                C[(size_t)(r + j) * OUT_F + c] = acc[m][n][j];
        }
}

extern "C" void kernel_launch(void* const* d_in, const int* in_sizes, int n_in,
                              void* d_out, int out_size, void* d_ws, size_t ws_size,
                              hipStream_t stream) {
    const float* x = (const float*)d_in[0];
    const int* qw = (const int*)d_in[1];
    const int* qz = (const int*)d_in[2];
    const float* sc = (const float*)d_in[3];
    float* out = (float*)d_out;

    const size_t xb_elems = (size_t)TOKENS * IN_F;
    const size_t wb_elems = (size_t)OUT_F * IN_F;
    const size_t need = (xb_elems + wb_elems) * sizeof(short);

    if (ws_size >= need) {
        short* xb = (short*)d_ws;
        short* wb = xb + xb_elems;
        cvt_x_kernel<<<(TOKENS * IN_F / 8) / 256, 256, 0, stream>>>(x, xb);
        dequant_w_kernel<<<(OUT_F * PACKS) / 256, 256, 0, stream>>>(qw, qz, sc, wb);
        const int ngemm = (TOKENS / BM) * (OUT_F / BN);   // 688
        gemm256_kernel<<<ngemm, 512, 0, stream>>>(xb, wb, out);
    } else {
        const int ngemm = (TOKENS / 128) * (OUT_F / 128);
        gemm_fused_kernel<<<ngemm, 256, 0, stream>>>(x, qw, qz, sc, out);
    }
}